// Round 13
// baseline (461.024 us; speedup 1.0000x reference)
//
#include <hip/hip_runtime.h>

// CustomRNN: B=2048, T=512, I=1, H=64.
// Evolution (rocprof us): R0 172 LDS-BW | R2 158 | R5 134 (DPP butterfly,
//  prev best) | R9 171 (shfl=same LDS pipe) | R11 280 MFMA recurrence
//  CORRECT but spilled (VGPR 60) | R12 241: spills fixed (VGPR 132), now
//  65% of the 1130cy step is dependency STALL: one wave per SIMD has
//  nothing to issue during MFMA/TRANS latency (in-order wave).
// R13 (this): fill the stalls with a SECOND independent chain in the
//  same wave + cheapen tanh.
//   - One wave = TWO 16-batch groups (32 batches/wave, 64 waves). W
//     fragments + bias/wih registers SHARED; chain A and B instruction
//     streams independent -> compiler fills A's stalls with B's issue.
//     Round = max(2 x issue ~700, dep path ~300) -> ~350-450cy/step/chain
//     vs 1130.
//   - tanh(a) = 1 - 2*rcp(1 + exp2(a*2.885390082)): 5 ops vs 8, correct
//     saturation at +-1 (exp2->0 => -1; exp2->inf => rcp->0 => +1).
//   - pack h via cvt_pkrtz pairs; fc epilogue reads f16 hb (end only).
//  Fragment identity (R11-proven, absmax 2e-3): with A=W[16mt+c15][16kt+4g+r],
//  B=h, D[4g+r][c15] == B[4g+r][c15] lane mapping -> D tile mt IS B tile
//  kt=mt after in-lane tanh+cvt. Zero transport, zero LDS, zero barriers.

typedef float v4f __attribute__((ext_vector_type(4)));
typedef float f32x4 __attribute__((ext_vector_type(4)));
typedef _Float16 f16;
typedef _Float16 f16x4 __attribute__((ext_vector_type(4)));
typedef int i32x2 __attribute__((ext_vector_type(2)));

#define MFMA_AB(A, B, C) __builtin_amdgcn_mfma_f32_16x16x16f16((A), (B), (C), 0, 0, 0)

#define NBW 32  // batches per wave (2 chains x MFMA N=16)

__device__ __forceinline__ f16x4 pack4(float a, float b, float c, float d) {
    const i32x2 p = {
        __builtin_bit_cast(int, __builtin_amdgcn_cvt_pkrtz(a, b)),
        __builtin_bit_cast(int, __builtin_amdgcn_cvt_pkrtz(c, d))};
    return __builtin_bit_cast(f16x4, p);
}

__global__ __launch_bounds__(64)
__attribute__((amdgpu_waves_per_eu(1, 1)))  // full VGPR budget: no spills
void rnn_fused(
    const float* __restrict__ x,      // [B, T, 1]
    const float* __restrict__ W_ih,   // [64, 1]
    const float* __restrict__ W_hh,   // [64, 64]
    const float* __restrict__ b_ih,   // [64]
    const float* __restrict__ b_hh,   // [64]
    const float* __restrict__ fc_w,   // [1, 64]
    const float* __restrict__ fc_b,   // [1]
    float* __restrict__ out,          // [B, 1]
    int B, int T)
{
    const int lane = threadIdx.x & 63;
    const int g    = lane >> 4;   // fragment outer group
    const int c15  = lane & 15;   // A row / B,D column (= local batch)
    const int b0   = blockIdx.x * NBW;

    // ---- W_hh as A-fragments (SHARED by both chains): 32 VGPRs.
    f16x4 wf[4][4];
#pragma unroll
    for (int mt = 0; mt < 4; ++mt) {
#pragma unroll
        for (int kt = 0; kt < 4; ++kt) {
            const v4f t = *(const v4f*)(W_hh + (16 * mt + c15) * 64 + 16 * kt + 4 * g);
            wf[mt][kt] = (f16x4){(f16)t.x, (f16)t.y, (f16)t.z, (f16)t.w};
        }
    }

    // ---- per-lane bias / W_ih for D rows j = 16*mt + 4*g + r (shared).
    float biasv[16], wihv[16];
#pragma unroll
    for (int mt = 0; mt < 4; ++mt)
#pragma unroll
        for (int r = 0; r < 4; ++r) {
            const int j = 16 * mt + 4 * g + r;
            biasv[4 * mt + r] = b_ih[j] + b_hh[j];
            wihv[4 * mt + r]  = W_ih[j];
        }

    // ---- h state, both chains, as B-fragments.
    f16x4 hbA[4], hbB[4];
#pragma unroll
    for (int kt = 0; kt < 4; ++kt) { hbA[kt] = (f16x4){0,0,0,0}; hbB[kt] = (f16x4){0,0,0,0}; }

    int biA = b0 + c15;      if (biA >= B) biA = B - 1;
    int biB = b0 + 16 + c15; if (biB >= B) biB = B - 1;
    const float* xpA = x + (size_t)biA * T;
    const float* xpB = x + (size_t)biB * T;

    // x double-buffers, 8 steps ahead (off the h-chain).
    v4f xa0 = *(const v4f*)(xpA),     xa1 = *(const v4f*)(xpA + 4);
    v4f xb0 = *(const v4f*)(xpB),     xb1 = *(const v4f*)(xpB + 4);

    for (int t0 = 0; t0 < T; t0 += 8) {
        v4f na0 = xa0, na1 = xa1, nb0 = xb0, nb1 = xb1;
        if (t0 + 8 < T) {
            na0 = *(const v4f*)(xpA + t0 + 8);  na1 = *(const v4f*)(xpA + t0 + 12);
            nb0 = *(const v4f*)(xpB + t0 + 8);  nb1 = *(const v4f*)(xpB + t0 + 12);
        }
        const float xsA[8] = {xa0.x, xa0.y, xa0.z, xa0.w, xa1.x, xa1.y, xa1.z, xa1.w};
        const float xsB[8] = {xb0.x, xb0.y, xb0.z, xb0.w, xb1.x, xb1.y, xb1.z, xb1.w};

#pragma unroll
        for (int s = 0; s < 8; ++s) {
            const float xvA = xsA[s], xvB = xsB[s];
            f32x4 dA[4], dB[4];
            // MFMA phase, both chains (independent streams interleaved).
#pragma unroll
            for (int mt = 0; mt < 4; ++mt) {
                f32x4 a0, a1, b0v, b1v;
#pragma unroll
                for (int r = 0; r < 4; ++r) {
                    a0[r]  = __builtin_fmaf(xvA, wihv[4 * mt + r], biasv[4 * mt + r]);
                    b0v[r] = __builtin_fmaf(xvB, wihv[4 * mt + r], biasv[4 * mt + r]);
                    a1[r] = 0.0f; b1v[r] = 0.0f;
                }
                a0  = MFMA_AB(wf[mt][0], hbA[0], a0);
                b0v = MFMA_AB(wf[mt][0], hbB[0], b0v);
                a1  = MFMA_AB(wf[mt][2], hbA[2], a1);
                b1v = MFMA_AB(wf[mt][2], hbB[2], b1v);
                a0  = MFMA_AB(wf[mt][1], hbA[1], a0);
                b0v = MFMA_AB(wf[mt][1], hbB[1], b0v);
                a1  = MFMA_AB(wf[mt][3], hbA[3], a1);
                b1v = MFMA_AB(wf[mt][3], hbB[3], b1v);
                dA[mt] = a0 + a1;
                dB[mt] = b0v + b1v;
            }
            // tanh + pack, both chains: t = 1 - 2*rcp(1 + exp2(a*k)).
#pragma unroll
            for (int mt = 0; mt < 4; ++mt) {
                float tA[4], tB[4];
#pragma unroll
                for (int r = 0; r < 4; ++r) {
                    const float eA = __builtin_amdgcn_exp2f(dA[mt][r] * 2.885390082f);
                    const float eB = __builtin_amdgcn_exp2f(dB[mt][r] * 2.885390082f);
                    tA[r] = __builtin_fmaf(-2.0f, __builtin_amdgcn_rcpf(1.0f + eA), 1.0f);
                    tB[r] = __builtin_fmaf(-2.0f, __builtin_amdgcn_rcpf(1.0f + eB), 1.0f);
                }
                hbA[mt] = pack4(tA[0], tA[1], tA[2], tA[3]);
                hbB[mt] = pack4(tB[0], tB[1], tB[2], tB[3]);
            }
        }
        xa0 = na0; xa1 = na1; xb0 = nb0; xb1 = nb1;
    }

    // ---- fc epilogue (end-of-kernel, off the hot path): read f16 hb.
    float pA = 0.0f, pB = 0.0f;
#pragma unroll
    for (int mt = 0; mt < 4; ++mt)
#pragma unroll
        for (int r = 0; r < 4; ++r) {
            const float fw = fc_w[16 * mt + 4 * g + r];
            pA = __builtin_fmaf((float)hbA[mt][r], fw, pA);
            pB = __builtin_fmaf((float)hbB[mt][r], fw, pB);
        }
    pA += __shfl_xor(pA, 16, 64);  pA += __shfl_xor(pA, 32, 64);
    pB += __shfl_xor(pB, 16, 64);  pB += __shfl_xor(pB, 32, 64);
    if (lane < 16) {
        if (b0 + lane < B)      out[b0 + lane]      = pA + fc_b[0];
        if (b0 + 16 + lane < B) out[b0 + 16 + lane] = pB + fc_b[0];
    }
}

extern "C" void kernel_launch(void* const* d_in, const int* in_sizes, int n_in,
                              void* d_out, int out_size, void* d_ws, size_t ws_size,
                              hipStream_t stream) {
    const float* x    = (const float*)d_in[0];
    const float* W_ih = (const float*)d_in[1];
    const float* W_hh = (const float*)d_in[2];
    const float* b_ih = (const float*)d_in[3];
    const float* b_hh = (const float*)d_in[4];
    const float* fc_w = (const float*)d_in[5];
    const float* fc_b = (const float*)d_in[6];
    float* out = (float*)d_out;

    const int B = out_size;          // output is [B, 1]
    const int T = in_sizes[0] / B;   // I == 1, so x has B*T elements

    const int blocks = (B + NBW - 1) / NBW;
    rnn_fused<<<blocks, 64, 0, stream>>>(x, W_ih, W_hh, b_ih, b_hh,
                                         fc_w, fc_b, out, B, T);
}